// Round 14
// baseline (446.586 us; speedup 1.0000x reference)
//
#include <hip/hip_runtime.h>
#include <math.h>

#define BB 2
#define NN 8192
#define DD 512

static const float INV_SCALE = 0.04419417382415922f; // 1/sqrt(512)

typedef short s16x8 __attribute__((ext_vector_type(8)));
typedef unsigned short u16x8 __attribute__((ext_vector_type(8)));
typedef float f32x4 __attribute__((ext_vector_type(4)));

#define AS1 __attribute__((address_space(1)))
#define AS3 __attribute__((address_space(3)))

__device__ __forceinline__ unsigned short bfbits(__bf16 h) {
    return __builtin_bit_cast(unsigned short, h);
}

__device__ __forceinline__ float b2f(unsigned short u) {
    unsigned int x = (unsigned int)u << 16;
    return __builtin_bit_cast(float, x);
}

__device__ __forceinline__ void gll16(const void* g, void* l) {
    __builtin_amdgcn_global_load_lds((const AS1 unsigned int*)g, (AS3 unsigned int*)l, 16, 0, 0);
}

__device__ __forceinline__ f32x4 ntload4(const float* p) {
    return __builtin_nontemporal_load((const f32x4*)p);
}

// ---------------------------------------------------------------------------
// convX: X f32 -> Xhi, Xlo bf16 (hi = rne(x), lo = rne(x - hi))
// ---------------------------------------------------------------------------
__global__ __launch_bounds__(256) void convx_k(
    const float* __restrict__ X, unsigned short* __restrict__ Xhi,
    unsigned short* __restrict__ Xlo)
{
    long i = (long)blockIdx.x * 256 + threadIdx.x;   // float4 index
    float4 x = ((const float4*)X)[i];
    __bf16 h0 = (__bf16)x.x, h1 = (__bf16)x.y, h2 = (__bf16)x.z, h3 = (__bf16)x.w;
    ushort4 hi4 = make_ushort4(bfbits(h0), bfbits(h1), bfbits(h2), bfbits(h3));
    __bf16 l0 = (__bf16)(x.x - (float)h0), l1 = (__bf16)(x.y - (float)h1);
    __bf16 l2 = (__bf16)(x.z - (float)h2), l3 = (__bf16)(x.w - (float)h3);
    ushort4 lo4 = make_ushort4(bfbits(l0), bfbits(l1), bfbits(l2), bfbits(l3));
    ((ushort4*)Xhi)[i] = hi4;
    ((ushort4*)Xlo)[i] = lo4;
}

// ---------------------------------------------------------------------------
// convW: Wqk[:, :512] -> QTh (hi only); Wqk[:, 512:] -> KTh/KTl (hi+lo);
//        Wv -> VTh (hi only).  All transposed to [n][k] bf16.
// ---------------------------------------------------------------------------
__global__ __launch_bounds__(256) void convw_k(
    const float* __restrict__ Wqk, const float* __restrict__ Wv,
    unsigned short* __restrict__ QTh, unsigned short* __restrict__ KTh,
    unsigned short* __restrict__ KTl, unsigned short* __restrict__ VTh)
{
    int i = blockIdx.x * 256 + threadIdx.x;          // < 786432
    if (i < 262144) {
        int n = i >> 9, k = i & 511;
        QTh[i] = bfbits((__bf16)Wqk[k * 1024 + n]);
    } else if (i < 524288) {
        int o = i - 262144; int n = o >> 9, k = o & 511;
        float val = Wqk[k * 1024 + 512 + n];
        __bf16 h = (__bf16)val;
        KTh[o] = bfbits(h);
        KTl[o] = bfbits((__bf16)(val - (float)h));
    } else {
        int o = i - 524288; int n = o >> 9, k = o & 511;
        VTh[o] = bfbits((__bf16)Wv[k * 512 + n]);
    }
}

// ===========================================================================
// BK=32 staging, 2-way-free swizzle (bank = (row*16+slot*4)%32):
//   sigma(row) = (row>>1)&3; LDS [row][slot ^ sigma(row)] 16B slots.
//   gll16 dest LINEAR; SOURCE byte col pre-swizzled ((l&3)^((l>>3)&3))<<4.
// ===========================================================================

// ---------------------------------------------------------------------------
// qkv MFMA GEMM: BK=32, dbuf, one barrier per K-step, 4 blocks/CU.
// EPI 0: fp32 C.  EPI 1: km fp32 + kmh bf16 (mask folded).  EPI 2: bf16 only.
// ---------------------------------------------------------------------------
template <int EPI, int NT>
__global__ __launch_bounds__(256, 4) void mfma_gemm(
    const unsigned short* __restrict__ A0, const unsigned short* __restrict__ A1,
    const unsigned short* __restrict__ B0, const unsigned short* __restrict__ B1,
    float* __restrict__ C, float* __restrict__ kmf,
    unsigned short* __restrict__ ubuf, const float* __restrict__ mask,
    int N, int K)
{
    constexpr int BK = 32;
    constexpr int TILE_SH = 128 * BK;        // 4096 shorts = 8 KB

    __shared__ unsigned short Asm[2 * TILE_SH];
    __shared__ unsigned short Bsm[2 * TILE_SH];

    const int t = threadIdx.x;
    const int wv = t >> 6, lane = t & 63;
    const int wm = wv >> 1, wn = wv & 1;
    const long m0 = blockIdx.x * 128;
    const int n0 = blockIdx.y * 128;

    f32x4 acc[4][4];
#pragma unroll
    for (int i = 0; i < 4; ++i)
#pragma unroll
        for (int j = 0; j < 4; ++j) acc[i][j] = {0.f, 0.f, 0.f, 0.f};

    const int swz = ((lane & 3) ^ ((lane >> 3) & 3)) << 4;  // src byte pre-swz
    auto stageA = [&](int term, int k0, int buf) {
        const unsigned short* Ab = (term < 2) ? A0 : A1;
#pragma unroll
        for (int u = 0; u < 2; ++u) {
            int c = wv * 2 + u;                       // chunk 0..7
            int row = c * 16 + (lane >> 2);
            gll16((const char*)Ab + ((m0 + row) * (long)K + k0) * 2 + swz,
                  (char*)Asm + buf * (TILE_SH * 2) + c * 1024);
        }
    };
    auto stageB = [&](int term, int k0, int buf) {
        const unsigned short* Bb = (NT == 3 && term == 1) ? B1 : B0;
#pragma unroll
        for (int u = 0; u < 2; ++u) {
            int c = wv * 2 + u;
            int row = c * 16 + (lane >> 2);
            gll16((const char*)Bb + ((long)(n0 + row) * K + k0) * 2 + swz,
                  (char*)Bsm + buf * (TILE_SH * 2) + c * 1024);
        }
    };

    stageA(0, 0, 0);
    stageB(0, 0, 0);
    __syncthreads();

    const int NTILES = NT * (K / BK);
    int cur = 0, term = 0, k0 = 0;
    const int g = lane >> 4;

#pragma unroll 2
    for (int tt = 0; tt < NTILES; ++tt) {
        int k0n = k0 + BK, termn = term;
        if (k0n == K) { k0n = 0; ++termn; }
        const bool hasNext = (tt + 1 < NTILES);

        if (hasNext) {
            stageA(termn, k0n, cur ^ 1);
            stageB(termn, k0n, cur ^ 1);
        }

        s16x8 av[4], bv[4];
#pragma unroll
        for (int f = 0; f < 4; ++f) {
            int ra = wm * 64 + f * 16 + (lane & 15);
            int rb = wn * 64 + f * 16 + (lane & 15);
            av[f] = *(const s16x8*)(Asm + cur * TILE_SH + ra * BK
                     + ((g ^ ((ra >> 1) & 3)) << 3));
            bv[f] = *(const s16x8*)(Bsm + cur * TILE_SH + rb * BK
                     + ((g ^ ((rb >> 1) & 3)) << 3));
        }
#pragma unroll
        for (int fm = 0; fm < 4; ++fm)
#pragma unroll
            for (int fn = 0; fn < 4; ++fn)
                acc[fm][fn] = __builtin_amdgcn_mfma_f32_16x16x32_bf16(
                    av[fm], bv[fn], acc[fm][fn], 0, 0, 0);

        __syncthreads();
        cur ^= 1; term = termn; k0 = k0n;
    }

    const long rbase = m0 + wm * 64;
    const int cbase = n0 + wn * 64;

#pragma unroll
    for (int fm = 0; fm < 4; ++fm) {
        long rb = rbase + fm * 16 + ((lane >> 4) << 2);
#pragma unroll
        for (int fn = 0; fn < 4; ++fn) {
            int c = cbase + fn * 16 + (lane & 15);
            if constexpr (EPI == 0) {
#pragma unroll
                for (int j = 0; j < 4; ++j)
                    C[(rb + j) * (long)N + c] = acc[fm][fn][j];
            } else if constexpr (EPI == 1) {
#pragma unroll
                for (int j = 0; j < 4; ++j) {
                    float kv = acc[fm][fn][j] * mask[rb + j];
                    kmf [(rb + j) * 512L + c] = kv;
                    ubuf[(rb + j) * 512L + c] = bfbits((__bf16)kv);
                }
            } else {
#pragma unroll
                for (int j = 0; j < 4; ++j)
                    ubuf[(rb + j) * 512L + c] = bfbits((__bf16)acc[fm][fn][j]);
            }
        }
    }
}

// ---------------------------------------------------------------------------
// S-GEMM with S-through-LDS adj sweep (r13, unchanged — proven best).
// ---------------------------------------------------------------------------
__global__ __launch_bounds__(256, 5) void sq_gemm(
    const unsigned short* __restrict__ qh,   // [16384][512] bf16
    const unsigned short* __restrict__ kmh,  // [B][8192][512] bf16
    const float* __restrict__ adj,           // [B][8192][8192] f32
    float* __restrict__ w)                   // [16384] atomic accum
{
    constexpr int BK = 32;
    constexpr int TILE_SH = 128 * BK;        // 4096 shorts = 8 KB

    __shared__ __align__(16) char smem[32768];
    unsigned short* Asm = (unsigned short*)smem;             // 2 bufs: 16 KB
    unsigned short* Bsm = (unsigned short*)(smem + 16384);   // 2 bufs: 16 KB
    unsigned short* Sh = (unsigned short*)smem;              // reuse: 128x128 bf16

    const int t = threadIdx.x;
    const int wv = t >> 6, lane = t & 63;
    const int wm = wv >> 1, wn = wv & 1;

    // bijective 2-D XCD swizzle: xcd(3b) | z(1b) | jhi(3b) | ii(3b) | jj(3b)
    const int bid = (int)blockIdx.x;
    const int xcd = bid & 7, s = bid >> 3;
    const int z = s >> 9, r = s & 511;
    const int jj = r & 7, ii = (r >> 3) & 7, jhi = r >> 6;
    const int i_tile = xcd * 8 + ii;         // 0..63
    const int j_tile = jhi * 8 + jj;         // 0..63

    const long m0 = (long)z * NN + (long)i_tile * 128;   // flat q row
    const int n0 = j_tile * 128;                         // j within batch
    const unsigned short* Bz = kmh + (long)z * NN * 512;

    f32x4 acc[4][4];
#pragma unroll
    for (int i = 0; i < 4; ++i)
#pragma unroll
        for (int j = 0; j < 4; ++j) acc[i][j] = {0.f, 0.f, 0.f, 0.f};

    const int swz = ((lane & 3) ^ ((lane >> 3) & 3)) << 4;
    auto stageA = [&](int k0, int buf) {
#pragma unroll
        for (int u = 0; u < 2; ++u) {
            int c = wv * 2 + u;
            int row = c * 16 + (lane >> 2);
            gll16((const char*)qh + ((m0 + row) * 512L + k0) * 2 + swz,
                  (char*)Asm + buf * (TILE_SH * 2) + c * 1024);
        }
    };
    auto stageB = [&](int k0, int buf) {
#pragma unroll
        for (int u = 0; u < 2; ++u) {
            int c = wv * 2 + u;
            int row = c * 16 + (lane >> 2);
            gll16((const char*)Bz + ((long)(n0 + row) * 512 + k0) * 2 + swz,
                  (char*)Bsm + buf * (TILE_SH * 2) + c * 1024);
        }
    };

    stageA(0, 0);
    stageB(0, 0);
    __syncthreads();

    const int g = lane >> 4;
#pragma unroll 2
    for (int tt = 0; tt < 16; ++tt) {        // K = 512 = 16 x 32
        const int cur = tt & 1;
        const bool hasNext = (tt + 1 < 16);
        if (hasNext) {
            stageA((tt + 1) * BK, cur ^ 1);
            stageB((tt + 1) * BK, cur ^ 1);
        }

        s16x8 av[4], bv[4];
#pragma unroll
        for (int f = 0; f < 4; ++f) {
            int ra = wm * 64 + f * 16 + (lane & 15);
            int rb = wn * 64 + f * 16 + (lane & 15);
            av[f] = *(const s16x8*)(Asm + cur * TILE_SH + ra * BK
                     + ((g ^ ((ra >> 1) & 3)) << 3));
            bv[f] = *(const s16x8*)(Bsm + cur * TILE_SH + rb * BK
                     + ((g ^ ((rb >> 1) & 3)) << 3));
        }
#pragma unroll
        for (int fm = 0; fm < 4; ++fm)
#pragma unroll
            for (int fn = 0; fn < 4; ++fn)
                acc[fm][fn] = __builtin_amdgcn_mfma_f32_16x16x32_bf16(
                    av[fm], bv[fn], acc[fm][fn], 0, 0, 0);

        __syncthreads();
    }
    // last iteration ended with __syncthreads(): Asm/Bsm free for reuse.

    // ---- S (bf16, full 128x128) -> LDS; acc dies here ----
    const int g2 = lane >> 4;                // == (rr>>2)&3 for our rows
#pragma unroll
    for (int fm = 0; fm < 4; ++fm) {
#pragma unroll
        for (int fn = 0; fn < 4; ++fn) {
            int c = wn * 64 + fn * 16 + (lane & 15);
            int slotx = ((((c >> 2) ^ (g2 << 2)) << 2) | (c & 3));
#pragma unroll
            for (int j = 0; j < 4; ++j) {
                int rr = wm * 64 + fm * 16 + (g2 << 2) + j;
                Sh[rr * 128 + slotx] = bfbits((__bf16)acc[fm][fn][j]);
            }
        }
    }
    __syncthreads();

    // ---- coalesced nontemporal adj sweep (no accumulators live) ----
    const float* adjZ = adj + (long)z * NN * NN;
    const int li0 = i_tile * 128;
    float* wz = w + (long)z * NN;

#pragma unroll 1
    for (int half = 0; half < 2; ++half) {
        f32x4 aj[8];
#pragma unroll
        for (int i = 0; i < 8; ++i) {
            int f = t + (half * 8 + i) * 256;    // 0..4095
            int rr = f >> 5, c4 = f & 31;
            aj[i] = ntload4(adjZ + (long)(li0 + rr) * NN + n0 + c4 * 4);
        }
#pragma unroll
        for (int i = 0; i < 8; ++i) {
            int f = t + (half * 8 + i) * 256;
            int rr = f >> 5, c4 = f & 31;
            int ps = (c4 ^ (((rr >> 2) & 3) << 2)) << 2;
            ushort4 sb = *(const ushort4*)(Sh + rr * 128 + ps);
            float p = aj[i][0] * b2f(sb.x) + aj[i][1] * b2f(sb.y)
                    + aj[i][2] * b2f(sb.z) + aj[i][3] * b2f(sb.w);
            p += __shfl_xor(p, 1);  p += __shfl_xor(p, 2);
            p += __shfl_xor(p, 4);  p += __shfl_xor(p, 8);
            p += __shfl_xor(p, 16);
            if ((t & 31) == 0) atomicAdd(wz + li0 + rr, p);
        }
    }
}

// ---------------------------------------------------------------------------
__global__ __launch_bounds__(256) void fixup_k(
    float* __restrict__ w, const float* __restrict__ mask)
{
    int i = blockIdx.x * 256 + threadIdx.x;
    w[i] *= INV_SCALE * mask[i];
}

// ---------------------------------------------------------------------------
// Refinement: exact fp32 recompute of w for rows near the max.
// ---------------------------------------------------------------------------
__global__ __launch_bounds__(256) void wmax_k(const float* __restrict__ w,
                                              float* __restrict__ wmax)
{
    const int b = blockIdx.x;
    const float* wr = w + (long)b * NN;
    const int t = threadIdx.x;
    float m = -3.4e38f;
    for (int i = t; i < NN; i += 256) m = fmaxf(m, wr[i]);
#pragma unroll
    for (int o = 32; o > 0; o >>= 1) m = fmaxf(m, __shfl_down(m, o));
    __shared__ float red[4];
    if ((t & 63) == 0) red[t >> 6] = m;
    __syncthreads();
    if (t == 0) wmax[b] = fmaxf(fmaxf(red[0], red[1]), fmaxf(red[2], red[3]));
}

__global__ __launch_bounds__(256) void select_k(
    const float* __restrict__ w, const float* __restrict__ wmax,
    int* __restrict__ count, int* __restrict__ cand)
{
    int i = blockIdx.x * 256 + threadIdx.x;  // 16384
    int b = i >> 13;
    if (w[i] >= wmax[b] - 15.f) {
        int p = atomicAdd(count, 1);
        if (p < 128) cand[p] = i;
    }
}

// exact fp32 q rows for candidates: qcand[y] = X[row] @ Wqk[:, :512]
__global__ __launch_bounds__(256) void qcand_k(
    const float* __restrict__ X, const float* __restrict__ Wqk,
    const int* __restrict__ cand, const int* __restrict__ count,
    float* __restrict__ qcand)
{
    int y = blockIdx.x;
    int cnt = *count; if (cnt > 128) cnt = 128;
    if (y >= cnt) return;
    const int row = cand[y];
    const float* Xr = X + (long)row * 512;
    const int t = threadIdx.x;
    __shared__ float xs[512];
    for (int k = t; k < 512; k += 256) xs[k] = Xr[k];
    __syncthreads();
    float a0 = 0.f, a1 = 0.f;
    for (int k = 0; k < 512; ++k) {
        float xv = xs[k];
        a0 += xv * Wqk[k * 1024 + t];
        a1 += xv * Wqk[k * 1024 + t + 256];
    }
    qcand[(long)y * 512 + t] = a0;
    qcand[(long)y * 512 + t + 256] = a1;
}

__global__ __launch_bounds__(256) void refine_k(
    const float* __restrict__ qcand, const float* __restrict__ km,
    const float* __restrict__ adj, const int* __restrict__ cand,
    const int* __restrict__ count, float* __restrict__ partial)
{
    int y = blockIdx.y;
    int cnt = *count; if (cnt > 128) cnt = 128;
    if (y >= cnt) return;
    const int row = cand[y];
    const int b = row >> 13, r = row & 8191;
    const int x = blockIdx.x;
    const int t = threadIdx.x, w = t >> 6, l = t & 63;

    const float* qr = qcand + (long)y * 512 + l * 8;
    const float4 q0 = *(const float4*)qr;
    const float4 q1 = *(const float4*)(qr + 4);
    const float* kmB = km + ((long)b << 13) * 512;
    const float* adjR = adj + (((long)b << 13) + r) * 8192L;

    float acc = 0.f;
    const int jbase = x * 128 + w * 32;
    for (int i = 0; i < 32; ++i) {
        int j = jbase + i;
        const float* kr = kmB + (long)j * 512 + l * 8;
        const float4 k0 = *(const float4*)kr;
        const float4 k1 = *(const float4*)(kr + 4);
        float d = q0.x * k0.x + q0.y * k0.y + q0.z * k0.z + q0.w * k0.w
                + q1.x * k1.x + q1.y * k1.y + q1.z * k1.z + q1.w * k1.w;
#pragma unroll
        for (int o = 32; o > 0; o >>= 1) d += __shfl_down(d, o);
        if (l == 0) acc += adjR[j] * d;
    }
    __shared__ float red[4];
    if (l == 0) red[w] = acc;
    __syncthreads();
    if (t == 0) partial[y * 64 + x] = red[0] + red[1] + red[2] + red[3];
}

__global__ __launch_bounds__(128) void apply_k(
    const int* __restrict__ cand, const int* __restrict__ count,
    const float* __restrict__ partial, const float* __restrict__ mask,
    float* __restrict__ w)
{
    int t = threadIdx.x;
    int cnt = *count; if (cnt > 128) cnt = 128;
    if (t < cnt) {
        float s = 0.f;
        for (int x = 0; x < 64; ++x) s += partial[t * 64 + x];
        int row = cand[t];
        w[row] = s * INV_SCALE * mask[row];
    }
}

// ---------------------------------------------------------------------------
__global__ __launch_bounds__(1024) void softmax_k(
    const float* __restrict__ w, float* __restrict__ p)
{
    const int b = blockIdx.x;
    const float* wr = w + (long)b * NN;
    float* pr = p + (long)b * NN;
    const int t = threadIdx.x;
    __shared__ float red[16];
    __shared__ float bmax, bsum;

    float m = -3.4e38f;
    for (int i = t; i < NN; i += 1024) m = fmaxf(m, wr[i]);
#pragma unroll
    for (int o = 32; o > 0; o >>= 1) m = fmaxf(m, __shfl_down(m, o));
    if ((t & 63) == 0) red[t >> 6] = m;
    __syncthreads();
    if (t == 0) {
        float mm = red[0];
        for (int i = 1; i < 16; ++i) mm = fmaxf(mm, red[i]);
        bmax = mm;
    }
    __syncthreads();
    const float M = bmax;

    float s = 0.f;
    for (int i = t; i < NN; i += 1024) s += expf(wr[i] - M);
#pragma unroll
    for (int o = 32; o > 0; o >>= 1) s += __shfl_down(s, o);
    __syncthreads();
    if ((t & 63) == 0) red[t >> 6] = s;
    __syncthreads();
    if (t == 0) {
        float ss = 0.f;
        for (int i = 0; i < 16; ++i) ss += red[i];
        bsum = ss;
    }
    __syncthreads();
    const float invS = 1.f / bsum;
    for (int i = t; i < NN; i += 1024) pr[i] = expf(wr[i] - M) * invS;
}

__global__ __launch_bounds__(256) void scale_k(
    const float* __restrict__ v, const float* __restrict__ p,
    float* __restrict__ out)
{
    const long i = (long)blockIdx.x * 256 + threadIdx.x;  // float4 index
    const int row = (int)(i >> 7);
    const float pv = p[row];
    float4 vv = ((const float4*)v)[i];
    vv.x *= pv; vv.y *= pv; vv.z *= pv; vv.w *= pv;
    ((float4*)out)[i] = vv;
}

// ---------------------------------------------------------------------------
extern "C" void kernel_launch(void* const* d_in, const int* in_sizes, int n_in,
                              void* d_out, int out_size, void* d_ws, size_t ws_size,
                              hipStream_t stream)
{
    const float* X    = (const float*)d_in[0];
    const float* adj  = (const float*)d_in[1];
    const float* mask = (const float*)d_in[2];
    const float* Wqk  = (const float*)d_in[3];
    const float* Wv   = (const float*)d_in[4];
    float* out = (float*)d_out;

    char* ws = (char*)d_ws;
    const long SZB = 33554432;  // 16384*512*4 bytes
    float* km_buf = (float*)(ws);                    // fp32 km (refine)
    float* v_buf  = (float*)(ws + SZB);
    unsigned short* Xhi = (unsigned short*)(ws + 2 * SZB);
    unsigned short* Xlo = Xhi + 8388608;
    unsigned short* qh  = (unsigned short*)(ws + 3 * SZB);            // 16.8 MB
    unsigned short* kmh = qh + 8388608;                               // 16.8 MB
    unsigned short* QTh = kmh + 8388608;             // 4 x 0.5 MB
    unsigned short* KTh = QTh + 262144;
    unsigned short* KTl = KTh + 262144;
    unsigned short* VTh = KTl + 262144;
    float* w_buf = (float*)(VTh + 262144);
    float* p_buf = w_buf + 16384;
    float* wmax  = p_buf + 16384;
    float* partial = wmax + 64;                      // 128*64
    float* qcand = partial + 8192;                   // 128*512
    int* count = (int*)(qcand + 65536);
    int* cand  = count + 64;

    hipError_t e0 = hipMemsetAsync(count, 0, 4, stream); (void)e0;
    hipError_t e1 = hipMemsetAsync(w_buf, 0, 16384 * 4, stream); (void)e1;

    convx_k<<<8192, 256, 0, stream>>>(X, Xhi, Xlo);
    convw_k<<<3072, 256, 0, stream>>>(Wqk, Wv, QTh, KTh, KTl, VTh);

    // km = (X @ Wk) * mask  (3-term split) -> km fp32 + kmh bf16
    mfma_gemm<1, 3><<<dim3(128, 4, 1), 256, 0, stream>>>(
        Xhi, Xlo, KTh, KTl, nullptr, km_buf, kmh, mask, 512, 512);

    // q = X @ Wq (single-term bf16) -> qh bf16 (fp32 q only needed per-cand)
    mfma_gemm<2, 1><<<dim3(128, 4, 1), 256, 0, stream>>>(
        Xhi, nullptr, QTh, nullptr, nullptr, nullptr, qh, nullptr, 512, 512);

    // v = X @ Wv (single-term bf16)
    mfma_gemm<0, 1><<<dim3(128, 4, 1), 256, 0, stream>>>(
        Xhi, nullptr, VTh, nullptr, v_buf, nullptr, nullptr, nullptr, 512, 512);

    // w += sum_j adj_ij * (q_i . km_j): S-GEMM tiles + S-through-LDS sweep
    sq_gemm<<<8192, 256, 0, stream>>>(qh, kmh, adj, w_buf);

    fixup_k<<<64, 256, 0, stream>>>(w_buf, mask);

    wmax_k<<<BB, 256, 0, stream>>>(w_buf, wmax);
    select_k<<<64, 256, 0, stream>>>(w_buf, wmax, count, cand);
    qcand_k<<<128, 256, 0, stream>>>(X, Wqk, cand, count, qcand);
    refine_k<<<dim3(64, 128, 1), 256, 0, stream>>>(qcand, km_buf, adj, cand, count, partial);
    apply_k<<<1, 128, 0, stream>>>(cand, count, partial, mask, w_buf);

    softmax_k<<<BB, 1024, 0, stream>>>(w_buf, p_buf);
    scale_k<<<8192, 256, 0, stream>>>(v_buf, p_buf, out);
}

// Round 15
// 439.410 us; speedup vs baseline: 1.0163x; 1.0163x over previous
//
#include <hip/hip_runtime.h>
#include <math.h>

#define BB 2
#define NN 8192
#define DD 512

static const float INV_SCALE = 0.04419417382415922f; // 1/sqrt(512)

typedef short s16x8 __attribute__((ext_vector_type(8)));
typedef unsigned short u16x8 __attribute__((ext_vector_type(8)));
typedef float f32x4 __attribute__((ext_vector_type(4)));

#define AS1 __attribute__((address_space(1)))
#define AS3 __attribute__((address_space(3)))

__device__ __forceinline__ unsigned short bfbits(__bf16 h) {
    return __builtin_bit_cast(unsigned short, h);
}

__device__ __forceinline__ float b2f(unsigned short u) {
    unsigned int x = (unsigned int)u << 16;
    return __builtin_bit_cast(float, x);
}

__device__ __forceinline__ void gll16(const void* g, void* l) {
    __builtin_amdgcn_global_load_lds((const AS1 unsigned int*)g, (AS3 unsigned int*)l, 16, 0, 0);
}

__device__ __forceinline__ f32x4 ntload4(const float* p) {
    return __builtin_nontemporal_load((const f32x4*)p);
}

// ---------------------------------------------------------------------------
// convX: X f32 -> Xhi, Xlo bf16 (hi = rne(x), lo = rne(x - hi))
// ---------------------------------------------------------------------------
__global__ __launch_bounds__(256) void convx_k(
    const float* __restrict__ X, unsigned short* __restrict__ Xhi,
    unsigned short* __restrict__ Xlo)
{
    long i = (long)blockIdx.x * 256 + threadIdx.x;   // float4 index
    float4 x = ((const float4*)X)[i];
    __bf16 h0 = (__bf16)x.x, h1 = (__bf16)x.y, h2 = (__bf16)x.z, h3 = (__bf16)x.w;
    ushort4 hi4 = make_ushort4(bfbits(h0), bfbits(h1), bfbits(h2), bfbits(h3));
    __bf16 l0 = (__bf16)(x.x - (float)h0), l1 = (__bf16)(x.y - (float)h1);
    __bf16 l2 = (__bf16)(x.z - (float)h2), l3 = (__bf16)(x.w - (float)h3);
    ushort4 lo4 = make_ushort4(bfbits(l0), bfbits(l1), bfbits(l2), bfbits(l3));
    ((ushort4*)Xhi)[i] = hi4;
    ((ushort4*)Xlo)[i] = lo4;
}

// ---------------------------------------------------------------------------
// convW: Wqk[:, :512] -> QTh (hi only); Wqk[:, 512:] -> KTh/KTl (hi+lo);
//        Wv -> VTh (hi only).  All transposed to [n][k] bf16.
// ---------------------------------------------------------------------------
__global__ __launch_bounds__(256) void convw_k(
    const float* __restrict__ Wqk, const float* __restrict__ Wv,
    unsigned short* __restrict__ QTh, unsigned short* __restrict__ KTh,
    unsigned short* __restrict__ KTl, unsigned short* __restrict__ VTh)
{
    int i = blockIdx.x * 256 + threadIdx.x;          // < 786432
    if (i < 262144) {
        int n = i >> 9, k = i & 511;
        QTh[i] = bfbits((__bf16)Wqk[k * 1024 + n]);
    } else if (i < 524288) {
        int o = i - 262144; int n = o >> 9, k = o & 511;
        float val = Wqk[k * 1024 + 512 + n];
        __bf16 h = (__bf16)val;
        KTh[o] = bfbits(h);
        KTl[o] = bfbits((__bf16)(val - (float)h));
    } else {
        int o = i - 524288; int n = o >> 9, k = o & 511;
        VTh[o] = bfbits((__bf16)Wv[k * 512 + n]);
    }
}

// ===========================================================================
// BK=32 staging, 2-way-free swizzle (bank = (row*16+slot*4)%32):
//   sigma(row) = (row>>1)&3; LDS [row][slot ^ sigma(row)] 16B slots.
//   gll16 dest LINEAR; SOURCE byte col pre-swizzled ((l&3)^((l>>3)&3))<<4.
// ===========================================================================

// ---------------------------------------------------------------------------
// qkv MFMA GEMM: BK=32, dbuf, one barrier per K-step, 4 blocks/CU.
// EPI 0: fp32 C.              EPI 1: km fp32 + kmh bf16 (mask folded).
// EPI 2: bf16 only (ubuf).    EPI 3: C = acc * rowscale[row]  (p-fused v).
// ---------------------------------------------------------------------------
template <int EPI, int NT>
__global__ __launch_bounds__(256, 4) void mfma_gemm(
    const unsigned short* __restrict__ A0, const unsigned short* __restrict__ A1,
    const unsigned short* __restrict__ B0, const unsigned short* __restrict__ B1,
    float* __restrict__ C, float* __restrict__ kmf,
    unsigned short* __restrict__ ubuf, const float* __restrict__ rowscale,
    int N, int K)
{
    constexpr int BK = 32;
    constexpr int TILE_SH = 128 * BK;        // 4096 shorts = 8 KB

    __shared__ unsigned short Asm[2 * TILE_SH];
    __shared__ unsigned short Bsm[2 * TILE_SH];

    const int t = threadIdx.x;
    const int wv = t >> 6, lane = t & 63;
    const int wm = wv >> 1, wn = wv & 1;
    const long m0 = blockIdx.x * 128;
    const int n0 = blockIdx.y * 128;

    f32x4 acc[4][4];
#pragma unroll
    for (int i = 0; i < 4; ++i)
#pragma unroll
        for (int j = 0; j < 4; ++j) acc[i][j] = {0.f, 0.f, 0.f, 0.f};

    const int swz = ((lane & 3) ^ ((lane >> 3) & 3)) << 4;  // src byte pre-swz
    auto stageA = [&](int term, int k0, int buf) {
        const unsigned short* Ab = (term < 2) ? A0 : A1;
#pragma unroll
        for (int u = 0; u < 2; ++u) {
            int c = wv * 2 + u;                       // chunk 0..7
            int row = c * 16 + (lane >> 2);
            gll16((const char*)Ab + ((m0 + row) * (long)K + k0) * 2 + swz,
                  (char*)Asm + buf * (TILE_SH * 2) + c * 1024);
        }
    };
    auto stageB = [&](int term, int k0, int buf) {
        const unsigned short* Bb = (NT == 3 && term == 1) ? B1 : B0;
#pragma unroll
        for (int u = 0; u < 2; ++u) {
            int c = wv * 2 + u;
            int row = c * 16 + (lane >> 2);
            gll16((const char*)Bb + ((long)(n0 + row) * K + k0) * 2 + swz,
                  (char*)Bsm + buf * (TILE_SH * 2) + c * 1024);
        }
    };

    stageA(0, 0, 0);
    stageB(0, 0, 0);
    __syncthreads();

    const int NTILES = NT * (K / BK);
    int cur = 0, term = 0, k0 = 0;
    const int g = lane >> 4;

#pragma unroll 2
    for (int tt = 0; tt < NTILES; ++tt) {
        int k0n = k0 + BK, termn = term;
        if (k0n == K) { k0n = 0; ++termn; }
        const bool hasNext = (tt + 1 < NTILES);

        if (hasNext) {
            stageA(termn, k0n, cur ^ 1);
            stageB(termn, k0n, cur ^ 1);
        }

        s16x8 av[4], bv[4];
#pragma unroll
        for (int f = 0; f < 4; ++f) {
            int ra = wm * 64 + f * 16 + (lane & 15);
            int rb = wn * 64 + f * 16 + (lane & 15);
            av[f] = *(const s16x8*)(Asm + cur * TILE_SH + ra * BK
                     + ((g ^ ((ra >> 1) & 3)) << 3));
            bv[f] = *(const s16x8*)(Bsm + cur * TILE_SH + rb * BK
                     + ((g ^ ((rb >> 1) & 3)) << 3));
        }
#pragma unroll
        for (int fm = 0; fm < 4; ++fm)
#pragma unroll
            for (int fn = 0; fn < 4; ++fn)
                acc[fm][fn] = __builtin_amdgcn_mfma_f32_16x16x32_bf16(
                    av[fm], bv[fn], acc[fm][fn], 0, 0, 0);

        __syncthreads();
        cur ^= 1; term = termn; k0 = k0n;
    }

    const long rbase = m0 + wm * 64;
    const int cbase = n0 + wn * 64;

#pragma unroll
    for (int fm = 0; fm < 4; ++fm) {
        long rb = rbase + fm * 16 + ((lane >> 4) << 2);
#pragma unroll
        for (int fn = 0; fn < 4; ++fn) {
            int c = cbase + fn * 16 + (lane & 15);
            if constexpr (EPI == 0) {
#pragma unroll
                for (int j = 0; j < 4; ++j)
                    C[(rb + j) * (long)N + c] = acc[fm][fn][j];
            } else if constexpr (EPI == 1) {
#pragma unroll
                for (int j = 0; j < 4; ++j) {
                    float kv = acc[fm][fn][j] * rowscale[rb + j];
                    kmf [(rb + j) * 512L + c] = kv;
                    ubuf[(rb + j) * 512L + c] = bfbits((__bf16)kv);
                }
            } else if constexpr (EPI == 2) {
#pragma unroll
                for (int j = 0; j < 4; ++j)
                    ubuf[(rb + j) * 512L + c] = bfbits((__bf16)acc[fm][fn][j]);
            } else {
#pragma unroll
                for (int j = 0; j < 4; ++j)
                    C[(rb + j) * 512L + c] = acc[fm][fn][j] * rowscale[rb + j];
            }
        }
    }
}

// ---------------------------------------------------------------------------
// S-GEMM with S-through-LDS adj sweep (r13, unchanged — proven best).
// ---------------------------------------------------------------------------
__global__ __launch_bounds__(256, 5) void sq_gemm(
    const unsigned short* __restrict__ qh,   // [16384][512] bf16
    const unsigned short* __restrict__ kmh,  // [B][8192][512] bf16
    const float* __restrict__ adj,           // [B][8192][8192] f32
    float* __restrict__ w)                   // [16384] atomic accum
{
    constexpr int BK = 32;
    constexpr int TILE_SH = 128 * BK;        // 4096 shorts = 8 KB

    __shared__ __align__(16) char smem[32768];
    unsigned short* Asm = (unsigned short*)smem;             // 2 bufs: 16 KB
    unsigned short* Bsm = (unsigned short*)(smem + 16384);   // 2 bufs: 16 KB
    unsigned short* Sh = (unsigned short*)smem;              // reuse: 128x128 bf16

    const int t = threadIdx.x;
    const int wv = t >> 6, lane = t & 63;
    const int wm = wv >> 1, wn = wv & 1;

    // bijective 2-D XCD swizzle: xcd(3b) | z(1b) | jhi(3b) | ii(3b) | jj(3b)
    const int bid = (int)blockIdx.x;
    const int xcd = bid & 7, s = bid >> 3;
    const int z = s >> 9, r = s & 511;
    const int jj = r & 7, ii = (r >> 3) & 7, jhi = r >> 6;
    const int i_tile = xcd * 8 + ii;         // 0..63
    const int j_tile = jhi * 8 + jj;         // 0..63

    const long m0 = (long)z * NN + (long)i_tile * 128;   // flat q row
    const int n0 = j_tile * 128;                         // j within batch
    const unsigned short* Bz = kmh + (long)z * NN * 512;

    f32x4 acc[4][4];
#pragma unroll
    for (int i = 0; i < 4; ++i)
#pragma unroll
        for (int j = 0; j < 4; ++j) acc[i][j] = {0.f, 0.f, 0.f, 0.f};

    const int swz = ((lane & 3) ^ ((lane >> 3) & 3)) << 4;
    auto stageA = [&](int k0, int buf) {
#pragma unroll
        for (int u = 0; u < 2; ++u) {
            int c = wv * 2 + u;
            int row = c * 16 + (lane >> 2);
            gll16((const char*)qh + ((m0 + row) * 512L + k0) * 2 + swz,
                  (char*)Asm + buf * (TILE_SH * 2) + c * 1024);
        }
    };
    auto stageB = [&](int k0, int buf) {
#pragma unroll
        for (int u = 0; u < 2; ++u) {
            int c = wv * 2 + u;
            int row = c * 16 + (lane >> 2);
            gll16((const char*)Bz + ((long)(n0 + row) * 512 + k0) * 2 + swz,
                  (char*)Bsm + buf * (TILE_SH * 2) + c * 1024);
        }
    };

    stageA(0, 0);
    stageB(0, 0);
    __syncthreads();

    const int g = lane >> 4;
#pragma unroll 2
    for (int tt = 0; tt < 16; ++tt) {        // K = 512 = 16 x 32
        const int cur = tt & 1;
        const bool hasNext = (tt + 1 < 16);
        if (hasNext) {
            stageA((tt + 1) * BK, cur ^ 1);
            stageB((tt + 1) * BK, cur ^ 1);
        }

        s16x8 av[4], bv[4];
#pragma unroll
        for (int f = 0; f < 4; ++f) {
            int ra = wm * 64 + f * 16 + (lane & 15);
            int rb = wn * 64 + f * 16 + (lane & 15);
            av[f] = *(const s16x8*)(Asm + cur * TILE_SH + ra * BK
                     + ((g ^ ((ra >> 1) & 3)) << 3));
            bv[f] = *(const s16x8*)(Bsm + cur * TILE_SH + rb * BK
                     + ((g ^ ((rb >> 1) & 3)) << 3));
        }
#pragma unroll
        for (int fm = 0; fm < 4; ++fm)
#pragma unroll
            for (int fn = 0; fn < 4; ++fn)
                acc[fm][fn] = __builtin_amdgcn_mfma_f32_16x16x32_bf16(
                    av[fm], bv[fn], acc[fm][fn], 0, 0, 0);

        __syncthreads();
    }
    // last iteration ended with __syncthreads(): Asm/Bsm free for reuse.

    // ---- S (bf16, full 128x128) -> LDS; acc dies here ----
    const int g2 = lane >> 4;                // == (rr>>2)&3 for our rows
#pragma unroll
    for (int fm = 0; fm < 4; ++fm) {
#pragma unroll
        for (int fn = 0; fn < 4; ++fn) {
            int c = wn * 64 + fn * 16 + (lane & 15);
            int slotx = ((((c >> 2) ^ (g2 << 2)) << 2) | (c & 3));
#pragma unroll
            for (int j = 0; j < 4; ++j) {
                int rr = wm * 64 + fm * 16 + (g2 << 2) + j;
                Sh[rr * 128 + slotx] = bfbits((__bf16)acc[fm][fn][j]);
            }
        }
    }
    __syncthreads();

    // ---- coalesced nontemporal adj sweep (no accumulators live) ----
    const float* adjZ = adj + (long)z * NN * NN;
    const int li0 = i_tile * 128;
    float* wz = w + (long)z * NN;

#pragma unroll 1
    for (int half = 0; half < 2; ++half) {
        f32x4 aj[8];
#pragma unroll
        for (int i = 0; i < 8; ++i) {
            int f = t + (half * 8 + i) * 256;    // 0..4095
            int rr = f >> 5, c4 = f & 31;
            aj[i] = ntload4(adjZ + (long)(li0 + rr) * NN + n0 + c4 * 4);
        }
#pragma unroll
        for (int i = 0; i < 8; ++i) {
            int f = t + (half * 8 + i) * 256;
            int rr = f >> 5, c4 = f & 31;
            int ps = (c4 ^ (((rr >> 2) & 3) << 2)) << 2;
            ushort4 sb = *(const ushort4*)(Sh + rr * 128 + ps);
            float p = aj[i][0] * b2f(sb.x) + aj[i][1] * b2f(sb.y)
                    + aj[i][2] * b2f(sb.z) + aj[i][3] * b2f(sb.w);
            p += __shfl_xor(p, 1);  p += __shfl_xor(p, 2);
            p += __shfl_xor(p, 4);  p += __shfl_xor(p, 8);
            p += __shfl_xor(p, 16);
            if ((t & 31) == 0) atomicAdd(wz + li0 + rr, p);
        }
    }
}

// ---------------------------------------------------------------------------
__global__ __launch_bounds__(256) void fixup_k(
    float* __restrict__ w, const float* __restrict__ mask)
{
    int i = blockIdx.x * 256 + threadIdx.x;
    w[i] *= INV_SCALE * mask[i];
}

// ---------------------------------------------------------------------------
// Refinement: exact fp32 recompute of w for rows near the max.
// wmaxsel: per-batch block — max reduce, then candidate scan (fused).
// ---------------------------------------------------------------------------
__global__ __launch_bounds__(256) void wmaxsel_k(
    const float* __restrict__ w, int* __restrict__ count,
    int* __restrict__ cand)
{
    const int b = blockIdx.x;
    const float* wr = w + (long)b * NN;
    const int t = threadIdx.x;
    float m = -3.4e38f;
    for (int i = t; i < NN; i += 256) m = fmaxf(m, wr[i]);
#pragma unroll
    for (int o = 32; o > 0; o >>= 1) m = fmaxf(m, __shfl_down(m, o));
    __shared__ float red[4];
    __shared__ float bm;
    if ((t & 63) == 0) red[t >> 6] = m;
    __syncthreads();
    if (t == 0) bm = fmaxf(fmaxf(red[0], red[1]), fmaxf(red[2], red[3]));
    __syncthreads();
    const float thr = bm - 15.f;
    for (int i = t; i < NN; i += 256) {
        if (wr[i] >= thr) {
            int p = atomicAdd(count, 1);
            if (p < 128) cand[p] = b * NN + i;
        }
    }
}

// exact fp32 q rows for candidates: qcand[y] = X[row] @ Wqk[:, :512]
__global__ __launch_bounds__(256) void qcand_k(
    const float* __restrict__ X, const float* __restrict__ Wqk,
    const int* __restrict__ cand, const int* __restrict__ count,
    float* __restrict__ qcand)
{
    int y = blockIdx.x;
    int cnt = *count; if (cnt > 128) cnt = 128;
    if (y >= cnt) return;
    const int row = cand[y];
    const float* Xr = X + (long)row * 512;
    const int t = threadIdx.x;
    __shared__ float xs[512];
    for (int k = t; k < 512; k += 256) xs[k] = Xr[k];
    __syncthreads();
    float a0 = 0.f, a1 = 0.f;
    for (int k = 0; k < 512; ++k) {
        float xv = xs[k];
        a0 += xv * Wqk[k * 1024 + t];
        a1 += xv * Wqk[k * 1024 + t + 256];
    }
    qcand[(long)y * 512 + t] = a0;
    qcand[(long)y * 512 + t + 256] = a1;
}

__global__ __launch_bounds__(256) void refine_k(
    const float* __restrict__ qcand, const float* __restrict__ km,
    const float* __restrict__ adj, const int* __restrict__ cand,
    const int* __restrict__ count, float* __restrict__ partial)
{
    int y = blockIdx.y;
    int cnt = *count; if (cnt > 128) cnt = 128;
    if (y >= cnt) return;
    const int row = cand[y];
    const int b = row >> 13, r = row & 8191;
    const int x = blockIdx.x;
    const int t = threadIdx.x, w = t >> 6, l = t & 63;

    const float* qr = qcand + (long)y * 512 + l * 8;
    const float4 q0 = *(const float4*)qr;
    const float4 q1 = *(const float4*)(qr + 4);
    const float* kmB = km + ((long)b << 13) * 512;
    const float* adjR = adj + (((long)b << 13) + r) * 8192L;

    float acc = 0.f;
    const int jbase = x * 128 + w * 32;
    for (int i = 0; i < 32; ++i) {
        int j = jbase + i;
        const float* kr = kmB + (long)j * 512 + l * 8;
        const float4 k0 = *(const float4*)kr;
        const float4 k1 = *(const float4*)(kr + 4);
        float d = q0.x * k0.x + q0.y * k0.y + q0.z * k0.z + q0.w * k0.w
                + q1.x * k1.x + q1.y * k1.y + q1.z * k1.z + q1.w * k1.w;
#pragma unroll
        for (int o = 32; o > 0; o >>= 1) d += __shfl_down(d, o);
        if (l == 0) acc += adjR[j] * d;
    }
    __shared__ float red[4];
    if (l == 0) red[w] = acc;
    __syncthreads();
    if (t == 0) partial[y * 64 + x] = red[0] + red[1] + red[2] + red[3];
}

__global__ __launch_bounds__(128) void apply_k(
    const int* __restrict__ cand, const int* __restrict__ count,
    const float* __restrict__ partial, const float* __restrict__ mask,
    float* __restrict__ w)
{
    int t = threadIdx.x;
    int cnt = *count; if (cnt > 128) cnt = 128;
    if (t < cnt) {
        float s = 0.f;
        for (int x = 0; x < 64; ++x) s += partial[t * 64 + x];
        int row = cand[t];
        w[row] = s * INV_SCALE * mask[row];
    }
}

// ---------------------------------------------------------------------------
__global__ __launch_bounds__(1024) void softmax_k(
    const float* __restrict__ w, float* __restrict__ p)
{
    const int b = blockIdx.x;
    const float* wr = w + (long)b * NN;
    float* pr = p + (long)b * NN;
    const int t = threadIdx.x;
    __shared__ float red[16];
    __shared__ float bmax, bsum;

    float m = -3.4e38f;
    for (int i = t; i < NN; i += 1024) m = fmaxf(m, wr[i]);
#pragma unroll
    for (int o = 32; o > 0; o >>= 1) m = fmaxf(m, __shfl_down(m, o));
    if ((t & 63) == 0) red[t >> 6] = m;
    __syncthreads();
    if (t == 0) {
        float mm = red[0];
        for (int i = 1; i < 16; ++i) mm = fmaxf(mm, red[i]);
        bmax = mm;
    }
    __syncthreads();
    const float M = bmax;

    float s = 0.f;
    for (int i = t; i < NN; i += 1024) s += expf(wr[i] - M);
#pragma unroll
    for (int o = 32; o > 0; o >>= 1) s += __shfl_down(s, o);
    __syncthreads();
    if ((t & 63) == 0) red[t >> 6] = s;
    __syncthreads();
    if (t == 0) {
        float ss = 0.f;
        for (int i = 0; i < 16; ++i) ss += red[i];
        bsum = ss;
    }
    __syncthreads();
    const float invS = 1.f / bsum;
    for (int i = t; i < NN; i += 1024) pr[i] = expf(wr[i] - M) * invS;
}

// ---------------------------------------------------------------------------
extern "C" void kernel_launch(void* const* d_in, const int* in_sizes, int n_in,
                              void* d_out, int out_size, void* d_ws, size_t ws_size,
                              hipStream_t stream)
{
    const float* X    = (const float*)d_in[0];
    const float* adj  = (const float*)d_in[1];
    const float* mask = (const float*)d_in[2];
    const float* Wqk  = (const float*)d_in[3];
    const float* Wv   = (const float*)d_in[4];
    float* out = (float*)d_out;

    char* ws = (char*)d_ws;
    const long SZB = 33554432;  // 16384*512*4 bytes
    float* km_buf = (float*)(ws);                    // fp32 km (refine)
    unsigned short* Xhi = (unsigned short*)(ws + SZB);
    unsigned short* Xlo = Xhi + 8388608;
    unsigned short* qh  = (unsigned short*)(ws + 2 * SZB);            // 16.8 MB
    unsigned short* kmh = qh + 8388608;                               // 16.8 MB
    unsigned short* QTh = kmh + 8388608;             // 4 x 0.5 MB
    unsigned short* KTh = QTh + 262144;
    unsigned short* KTl = KTh + 262144;
    unsigned short* VTh = KTl + 262144;
    float* w_buf = (float*)(VTh + 262144);
    float* p_buf = w_buf + 16384;
    float* partial = p_buf + 16384;                  // 128*64
    float* qcand = partial + 8192;                   // 128*512
    int* count = (int*)(qcand + 65536);
    int* cand  = count + 64;

    hipError_t e0 = hipMemsetAsync(count, 0, 4, stream); (void)e0;
    hipError_t e1 = hipMemsetAsync(w_buf, 0, 16384 * 4, stream); (void)e1;

    convx_k<<<8192, 256, 0, stream>>>(X, Xhi, Xlo);
    convw_k<<<3072, 256, 0, stream>>>(Wqk, Wv, QTh, KTh, KTl, VTh);

    // km = (X @ Wk) * mask  (3-term split) -> km fp32 + kmh bf16
    mfma_gemm<1, 3><<<dim3(128, 4, 1), 256, 0, stream>>>(
        Xhi, Xlo, KTh, KTl, nullptr, km_buf, kmh, mask, 512, 512);

    // q = X @ Wq (single-term bf16) -> qh bf16 (fp32 q only needed per-cand)
    mfma_gemm<2, 1><<<dim3(128, 4, 1), 256, 0, stream>>>(
        Xhi, nullptr, QTh, nullptr, nullptr, nullptr, qh, nullptr, 512, 512);

    // w += sum_j adj_ij * (q_i . km_j): S-GEMM tiles + S-through-LDS sweep
    sq_gemm<<<8192, 256, 0, stream>>>(qh, kmh, adj, w_buf);

    fixup_k<<<64, 256, 0, stream>>>(w_buf, mask);

    wmaxsel_k<<<BB, 256, 0, stream>>>(w_buf, count, cand);
    qcand_k<<<128, 256, 0, stream>>>(X, Wqk, cand, count, qcand);
    refine_k<<<dim3(64, 128, 1), 256, 0, stream>>>(qcand, km_buf, adj, cand, count, partial);
    apply_k<<<1, 128, 0, stream>>>(cand, count, partial, mask, w_buf);

    softmax_k<<<BB, 1024, 0, stream>>>(w_buf, p_buf);

    // out = p * (X @ Wv): v-GEMM moved post-softmax, p fused in epilogue
    mfma_gemm<3, 1><<<dim3(128, 4, 1), 256, 0, stream>>>(
        Xhi, nullptr, VTh, nullptr, out, nullptr, nullptr, p_buf, 512, 512);
}

// Round 16
// 431.408 us; speedup vs baseline: 1.0352x; 1.0185x over previous
//
#include <hip/hip_runtime.h>
#include <math.h>

#define BB 2
#define NN 8192
#define DD 512

static const float INV_SCALE = 0.04419417382415922f; // 1/sqrt(512)

typedef short s16x8 __attribute__((ext_vector_type(8)));
typedef unsigned short u16x8 __attribute__((ext_vector_type(8)));
typedef float f32x4 __attribute__((ext_vector_type(4)));

#define AS1 __attribute__((address_space(1)))
#define AS3 __attribute__((address_space(3)))

__device__ __forceinline__ unsigned short bfbits(__bf16 h) {
    return __builtin_bit_cast(unsigned short, h);
}

__device__ __forceinline__ float b2f(unsigned short u) {
    unsigned int x = (unsigned int)u << 16;
    return __builtin_bit_cast(float, x);
}

__device__ __forceinline__ void gll16(const void* g, void* l) {
    __builtin_amdgcn_global_load_lds((const AS1 unsigned int*)g, (AS3 unsigned int*)l, 16, 0, 0);
}

__device__ __forceinline__ f32x4 ntload4(const float* p) {
    return __builtin_nontemporal_load((const f32x4*)p);
}

// ---------------------------------------------------------------------------
// convX: X f32 -> Xhi, Xlo bf16 (hi = rne(x), lo = rne(x - hi))
// ---------------------------------------------------------------------------
__global__ __launch_bounds__(256) void convx_k(
    const float* __restrict__ X, unsigned short* __restrict__ Xhi,
    unsigned short* __restrict__ Xlo)
{
    long i = (long)blockIdx.x * 256 + threadIdx.x;   // float4 index
    float4 x = ((const float4*)X)[i];
    __bf16 h0 = (__bf16)x.x, h1 = (__bf16)x.y, h2 = (__bf16)x.z, h3 = (__bf16)x.w;
    ushort4 hi4 = make_ushort4(bfbits(h0), bfbits(h1), bfbits(h2), bfbits(h3));
    __bf16 l0 = (__bf16)(x.x - (float)h0), l1 = (__bf16)(x.y - (float)h1);
    __bf16 l2 = (__bf16)(x.z - (float)h2), l3 = (__bf16)(x.w - (float)h3);
    ushort4 lo4 = make_ushort4(bfbits(l0), bfbits(l1), bfbits(l2), bfbits(l3));
    ((ushort4*)Xhi)[i] = hi4;
    ((ushort4*)Xlo)[i] = lo4;
}

// ---------------------------------------------------------------------------
// convW: Wqk[:, :512] -> QTh (hi only); Wqk[:, 512:] -> KTh/KTl (hi+lo);
//        Wv -> VTh (hi only).  All transposed to [n][k] bf16.
// ---------------------------------------------------------------------------
__global__ __launch_bounds__(256) void convw_k(
    const float* __restrict__ Wqk, const float* __restrict__ Wv,
    unsigned short* __restrict__ QTh, unsigned short* __restrict__ KTh,
    unsigned short* __restrict__ KTl, unsigned short* __restrict__ VTh)
{
    int i = blockIdx.x * 256 + threadIdx.x;          // < 786432
    if (i < 262144) {
        int n = i >> 9, k = i & 511;
        QTh[i] = bfbits((__bf16)Wqk[k * 1024 + n]);
    } else if (i < 524288) {
        int o = i - 262144; int n = o >> 9, k = o & 511;
        float val = Wqk[k * 1024 + 512 + n];
        __bf16 h = (__bf16)val;
        KTh[o] = bfbits(h);
        KTl[o] = bfbits((__bf16)(val - (float)h));
    } else {
        int o = i - 524288; int n = o >> 9, k = o & 511;
        VTh[o] = bfbits((__bf16)Wv[k * 512 + n]);
    }
}

// ===========================================================================
// BK=32 staging, 2-way-free swizzle (bank = (row*16+slot*4)%32):
//   sigma(row) = (row>>1)&3; LDS [row][slot ^ sigma(row)] 16B slots.
//   gll16 dest LINEAR; SOURCE byte col pre-swizzled ((l&3)^((l>>3)&3))<<4.
// ===========================================================================

// ---------------------------------------------------------------------------
// qkv MFMA GEMM: BK=32, dbuf, one barrier per K-step, 4 blocks/CU.
// EPI 0: fp32 C.              EPI 1: km fp32 + kmh bf16 (mask folded).
// EPI 2: bf16 only (ubuf).    EPI 3: C = acc * rowscale[row]  (p-fused v).
// ---------------------------------------------------------------------------
template <int EPI, int NT>
__global__ __launch_bounds__(256, 4) void mfma_gemm(
    const unsigned short* __restrict__ A0, const unsigned short* __restrict__ A1,
    const unsigned short* __restrict__ B0, const unsigned short* __restrict__ B1,
    float* __restrict__ C, float* __restrict__ kmf,
    unsigned short* __restrict__ ubuf, const float* __restrict__ rowscale,
    int N, int K)
{
    constexpr int BK = 32;
    constexpr int TILE_SH = 128 * BK;        // 4096 shorts = 8 KB

    __shared__ unsigned short Asm[2 * TILE_SH];
    __shared__ unsigned short Bsm[2 * TILE_SH];

    const int t = threadIdx.x;
    const int wv = t >> 6, lane = t & 63;
    const int wm = wv >> 1, wn = wv & 1;
    const long m0 = blockIdx.x * 128;
    const int n0 = blockIdx.y * 128;

    f32x4 acc[4][4];
#pragma unroll
    for (int i = 0; i < 4; ++i)
#pragma unroll
        for (int j = 0; j < 4; ++j) acc[i][j] = {0.f, 0.f, 0.f, 0.f};

    const int swz = ((lane & 3) ^ ((lane >> 3) & 3)) << 4;  // src byte pre-swz
    auto stageA = [&](int term, int k0, int buf) {
        const unsigned short* Ab = (term < 2) ? A0 : A1;
#pragma unroll
        for (int u = 0; u < 2; ++u) {
            int c = wv * 2 + u;                       // chunk 0..7
            int row = c * 16 + (lane >> 2);
            gll16((const char*)Ab + ((m0 + row) * (long)K + k0) * 2 + swz,
                  (char*)Asm + buf * (TILE_SH * 2) + c * 1024);
        }
    };
    auto stageB = [&](int term, int k0, int buf) {
        const unsigned short* Bb = (NT == 3 && term == 1) ? B1 : B0;
#pragma unroll
        for (int u = 0; u < 2; ++u) {
            int c = wv * 2 + u;
            int row = c * 16 + (lane >> 2);
            gll16((const char*)Bb + ((long)(n0 + row) * K + k0) * 2 + swz,
                  (char*)Bsm + buf * (TILE_SH * 2) + c * 1024);
        }
    };

    stageA(0, 0, 0);
    stageB(0, 0, 0);
    __syncthreads();

    const int NTILES = NT * (K / BK);
    int cur = 0, term = 0, k0 = 0;
    const int g = lane >> 4;

#pragma unroll 2
    for (int tt = 0; tt < NTILES; ++tt) {
        int k0n = k0 + BK, termn = term;
        if (k0n == K) { k0n = 0; ++termn; }
        const bool hasNext = (tt + 1 < NTILES);

        if (hasNext) {
            stageA(termn, k0n, cur ^ 1);
            stageB(termn, k0n, cur ^ 1);
        }

        s16x8 av[4], bv[4];
#pragma unroll
        for (int f = 0; f < 4; ++f) {
            int ra = wm * 64 + f * 16 + (lane & 15);
            int rb = wn * 64 + f * 16 + (lane & 15);
            av[f] = *(const s16x8*)(Asm + cur * TILE_SH + ra * BK
                     + ((g ^ ((ra >> 1) & 3)) << 3));
            bv[f] = *(const s16x8*)(Bsm + cur * TILE_SH + rb * BK
                     + ((g ^ ((rb >> 1) & 3)) << 3));
        }
#pragma unroll
        for (int fm = 0; fm < 4; ++fm)
#pragma unroll
            for (int fn = 0; fn < 4; ++fn)
                acc[fm][fn] = __builtin_amdgcn_mfma_f32_16x16x32_bf16(
                    av[fm], bv[fn], acc[fm][fn], 0, 0, 0);

        __syncthreads();
        cur ^= 1; term = termn; k0 = k0n;
    }

    const long rbase = m0 + wm * 64;
    const int cbase = n0 + wn * 64;

#pragma unroll
    for (int fm = 0; fm < 4; ++fm) {
        long rb = rbase + fm * 16 + ((lane >> 4) << 2);
#pragma unroll
        for (int fn = 0; fn < 4; ++fn) {
            int c = cbase + fn * 16 + (lane & 15);
            if constexpr (EPI == 0) {
#pragma unroll
                for (int j = 0; j < 4; ++j)
                    C[(rb + j) * (long)N + c] = acc[fm][fn][j];
            } else if constexpr (EPI == 1) {
#pragma unroll
                for (int j = 0; j < 4; ++j) {
                    float kv = acc[fm][fn][j] * rowscale[rb + j];
                    kmf [(rb + j) * 512L + c] = kv;
                    ubuf[(rb + j) * 512L + c] = bfbits((__bf16)kv);
                }
            } else if constexpr (EPI == 2) {
#pragma unroll
                for (int j = 0; j < 4; ++j)
                    ubuf[(rb + j) * 512L + c] = bfbits((__bf16)acc[fm][fn][j]);
            } else {
#pragma unroll
                for (int j = 0; j < 4; ++j)
                    C[(rb + j) * 512L + c] = acc[fm][fn][j] * rowscale[rb + j];
            }
        }
    }
}

// ---------------------------------------------------------------------------
// S-GEMM with S-through-LDS adj sweep.  K-loop = r13 (proven).
// Sweep v2: 16 nontemporal loads in flight per thread (two named 8-deep
// batches, issued back-to-back before any consume) — deeper HBM pipeline.
// acc is dead before ajA/ajB live: peak VGPR ~80 < 102 budget, no spill.
// ---------------------------------------------------------------------------
__global__ __launch_bounds__(256, 5) void sq_gemm(
    const unsigned short* __restrict__ qh,   // [16384][512] bf16
    const unsigned short* __restrict__ kmh,  // [B][8192][512] bf16
    const float* __restrict__ adj,           // [B][8192][8192] f32
    float* __restrict__ w)                   // [16384] atomic accum
{
    constexpr int BK = 32;
    constexpr int TILE_SH = 128 * BK;        // 4096 shorts = 8 KB

    __shared__ __align__(16) char smem[32768];
    unsigned short* Asm = (unsigned short*)smem;             // 2 bufs: 16 KB
    unsigned short* Bsm = (unsigned short*)(smem + 16384);   // 2 bufs: 16 KB
    unsigned short* Sh = (unsigned short*)smem;              // reuse: 128x128 bf16

    const int t = threadIdx.x;
    const int wv = t >> 6, lane = t & 63;
    const int wm = wv >> 1, wn = wv & 1;

    // bijective 2-D XCD swizzle: xcd(3b) | z(1b) | jhi(3b) | ii(3b) | jj(3b)
    const int bid = (int)blockIdx.x;
    const int xcd = bid & 7, s = bid >> 3;
    const int z = s >> 9, r = s & 511;
    const int jj = r & 7, ii = (r >> 3) & 7, jhi = r >> 6;
    const int i_tile = xcd * 8 + ii;         // 0..63
    const int j_tile = jhi * 8 + jj;         // 0..63

    const long m0 = (long)z * NN + (long)i_tile * 128;   // flat q row
    const int n0 = j_tile * 128;                         // j within batch
    const unsigned short* Bz = kmh + (long)z * NN * 512;

    f32x4 acc[4][4];
#pragma unroll
    for (int i = 0; i < 4; ++i)
#pragma unroll
        for (int j = 0; j < 4; ++j) acc[i][j] = {0.f, 0.f, 0.f, 0.f};

    const int swz = ((lane & 3) ^ ((lane >> 3) & 3)) << 4;
    auto stageA = [&](int k0, int buf) {
#pragma unroll
        for (int u = 0; u < 2; ++u) {
            int c = wv * 2 + u;
            int row = c * 16 + (lane >> 2);
            gll16((const char*)qh + ((m0 + row) * 512L + k0) * 2 + swz,
                  (char*)Asm + buf * (TILE_SH * 2) + c * 1024);
        }
    };
    auto stageB = [&](int k0, int buf) {
#pragma unroll
        for (int u = 0; u < 2; ++u) {
            int c = wv * 2 + u;
            int row = c * 16 + (lane >> 2);
            gll16((const char*)Bz + ((long)(n0 + row) * 512 + k0) * 2 + swz,
                  (char*)Bsm + buf * (TILE_SH * 2) + c * 1024);
        }
    };

    stageA(0, 0);
    stageB(0, 0);
    __syncthreads();

    const int g = lane >> 4;
#pragma unroll 2
    for (int tt = 0; tt < 16; ++tt) {        // K = 512 = 16 x 32
        const int cur = tt & 1;
        const bool hasNext = (tt + 1 < 16);
        if (hasNext) {
            stageA((tt + 1) * BK, cur ^ 1);
            stageB((tt + 1) * BK, cur ^ 1);
        }

        s16x8 av[4], bv[4];
#pragma unroll
        for (int f = 0; f < 4; ++f) {
            int ra = wm * 64 + f * 16 + (lane & 15);
            int rb = wn * 64 + f * 16 + (lane & 15);
            av[f] = *(const s16x8*)(Asm + cur * TILE_SH + ra * BK
                     + ((g ^ ((ra >> 1) & 3)) << 3));
            bv[f] = *(const s16x8*)(Bsm + cur * TILE_SH + rb * BK
                     + ((g ^ ((rb >> 1) & 3)) << 3));
        }
#pragma unroll
        for (int fm = 0; fm < 4; ++fm)
#pragma unroll
            for (int fn = 0; fn < 4; ++fn)
                acc[fm][fn] = __builtin_amdgcn_mfma_f32_16x16x32_bf16(
                    av[fm], bv[fn], acc[fm][fn], 0, 0, 0);

        __syncthreads();
    }
    // last iteration ended with __syncthreads(): Asm/Bsm free for reuse.

    // ---- S (bf16, full 128x128) -> LDS; acc dies here ----
    const int g2 = lane >> 4;                // == (rr>>2)&3 for our rows
#pragma unroll
    for (int fm = 0; fm < 4; ++fm) {
#pragma unroll
        for (int fn = 0; fn < 4; ++fn) {
            int c = wn * 64 + fn * 16 + (lane & 15);
            int slotx = ((((c >> 2) ^ (g2 << 2)) << 2) | (c & 3));
#pragma unroll
            for (int j = 0; j < 4; ++j) {
                int rr = wm * 64 + fm * 16 + (g2 << 2) + j;
                Sh[rr * 128 + slotx] = bfbits((__bf16)acc[fm][fn][j]);
            }
        }
    }
    __syncthreads();

    // ---- coalesced nontemporal adj sweep: 16 loads in flight ----
    const float* adjZ = adj + (long)z * NN * NN;
    const int li0 = i_tile * 128;
    float* wz = w + (long)z * NN;

    f32x4 ajA[8], ajB[8];
#pragma unroll
    for (int i = 0; i < 8; ++i) {
        int f = t + i * 256;                 // float4 idx 0..2047
        int rr = f >> 5, c4 = f & 31;
        ajA[i] = ntload4(adjZ + (long)(li0 + rr) * NN + n0 + c4 * 4);
    }
#pragma unroll
    for (int i = 0; i < 8; ++i) {
        int f = t + (8 + i) * 256;           // 2048..4095
        int rr = f >> 5, c4 = f & 31;
        ajB[i] = ntload4(adjZ + (long)(li0 + rr) * NN + n0 + c4 * 4);
    }
#pragma unroll
    for (int i = 0; i < 8; ++i) {
        int f = t + i * 256;
        int rr = f >> 5, c4 = f & 31;
        int ps = (c4 ^ (((rr >> 2) & 3) << 2)) << 2;
        ushort4 sb = *(const ushort4*)(Sh + rr * 128 + ps);
        float p = ajA[i][0] * b2f(sb.x) + ajA[i][1] * b2f(sb.y)
                + ajA[i][2] * b2f(sb.z) + ajA[i][3] * b2f(sb.w);
        p += __shfl_xor(p, 1);  p += __shfl_xor(p, 2);
        p += __shfl_xor(p, 4);  p += __shfl_xor(p, 8);
        p += __shfl_xor(p, 16);
        if ((t & 31) == 0) atomicAdd(wz + li0 + rr, p);
    }
#pragma unroll
    for (int i = 0; i < 8; ++i) {
        int f = t + (8 + i) * 256;
        int rr = f >> 5, c4 = f & 31;
        int ps = (c4 ^ (((rr >> 2) & 3) << 2)) << 2;
        ushort4 sb = *(const ushort4*)(Sh + rr * 128 + ps);
        float p = ajB[i][0] * b2f(sb.x) + ajB[i][1] * b2f(sb.y)
                + ajB[i][2] * b2f(sb.z) + ajB[i][3] * b2f(sb.w);
        p += __shfl_xor(p, 1);  p += __shfl_xor(p, 2);
        p += __shfl_xor(p, 4);  p += __shfl_xor(p, 8);
        p += __shfl_xor(p, 16);
        if ((t & 31) == 0) atomicAdd(wz + li0 + rr, p);
    }
}

// ---------------------------------------------------------------------------
__global__ __launch_bounds__(256) void fixup_k(
    float* __restrict__ w, const float* __restrict__ mask)
{
    int i = blockIdx.x * 256 + threadIdx.x;
    w[i] *= INV_SCALE * mask[i];
}

// ---------------------------------------------------------------------------
// Refinement: exact fp32 recompute of w for rows near the max.
// ---------------------------------------------------------------------------
__global__ __launch_bounds__(256) void wmaxsel_k(
    const float* __restrict__ w, int* __restrict__ count,
    int* __restrict__ cand)
{
    const int b = blockIdx.x;
    const float* wr = w + (long)b * NN;
    const int t = threadIdx.x;
    float m = -3.4e38f;
    for (int i = t; i < NN; i += 256) m = fmaxf(m, wr[i]);
#pragma unroll
    for (int o = 32; o > 0; o >>= 1) m = fmaxf(m, __shfl_down(m, o));
    __shared__ float red[4];
    __shared__ float bm;
    if ((t & 63) == 0) red[t >> 6] = m;
    __syncthreads();
    if (t == 0) bm = fmaxf(fmaxf(red[0], red[1]), fmaxf(red[2], red[3]));
    __syncthreads();
    const float thr = bm - 15.f;
    for (int i = t; i < NN; i += 256) {
        if (wr[i] >= thr) {
            int p = atomicAdd(count, 1);
            if (p < 128) cand[p] = b * NN + i;
        }
    }
}

// exact fp32 q rows for candidates: qcand[y] = X[row] @ Wqk[:, :512]
__global__ __launch_bounds__(256) void qcand_k(
    const float* __restrict__ X, const float* __restrict__ Wqk,
    const int* __restrict__ cand, const int* __restrict__ count,
    float* __restrict__ qcand)
{
    int y = blockIdx.x;
    int cnt = *count; if (cnt > 128) cnt = 128;
    if (y >= cnt) return;
    const int row = cand[y];
    const float* Xr = X + (long)row * 512;
    const int t = threadIdx.x;
    __shared__ float xs[512];
    for (int k = t; k < 512; k += 256) xs[k] = Xr[k];
    __syncthreads();
    float a0 = 0.f, a1 = 0.f;
    for (int k = 0; k < 512; ++k) {
        float xv = xs[k];
        a0 += xv * Wqk[k * 1024 + t];
        a1 += xv * Wqk[k * 1024 + t + 256];
    }
    qcand[(long)y * 512 + t] = a0;
    qcand[(long)y * 512 + t + 256] = a1;
}

__global__ __launch_bounds__(256) void refine_k(
    const float* __restrict__ qcand, const float* __restrict__ km,
    const float* __restrict__ adj, const int* __restrict__ cand,
    const int* __restrict__ count, float* __restrict__ partial)
{
    int y = blockIdx.y;
    int cnt = *count; if (cnt > 128) cnt = 128;
    if (y >= cnt) return;
    const int row = cand[y];
    const int b = row >> 13, r = row & 8191;
    const int x = blockIdx.x;
    const int t = threadIdx.x, w = t >> 6, l = t & 63;

    const float* qr = qcand + (long)y * 512 + l * 8;
    const float4 q0 = *(const float4*)qr;
    const float4 q1 = *(const float4*)(qr + 4);
    const float* kmB = km + ((long)b << 13) * 512;
    const float* adjR = adj + (((long)b << 13) + r) * 8192L;

    float acc = 0.f;
    const int jbase = x * 128 + w * 32;
    for (int i = 0; i < 32; ++i) {
        int j = jbase + i;
        const float* kr = kmB + (long)j * 512 + l * 8;
        const float4 k0 = *(const float4*)kr;
        const float4 k1 = *(const float4*)(kr + 4);
        float d = q0.x * k0.x + q0.y * k0.y + q0.z * k0.z + q0.w * k0.w
                + q1.x * k1.x + q1.y * k1.y + q1.z * k1.z + q1.w * k1.w;
#pragma unroll
        for (int o = 32; o > 0; o >>= 1) d += __shfl_down(d, o);
        if (l == 0) acc += adjR[j] * d;
    }
    __shared__ float red[4];
    if (l == 0) red[w] = acc;
    __syncthreads();
    if (t == 0) partial[y * 64 + x] = red[0] + red[1] + red[2] + red[3];
}

__global__ __launch_bounds__(128) void apply_k(
    const int* __restrict__ cand, const int* __restrict__ count,
    const float* __restrict__ partial, const float* __restrict__ mask,
    float* __restrict__ w)
{
    int t = threadIdx.x;
    int cnt = *count; if (cnt > 128) cnt = 128;
    if (t < cnt) {
        float s = 0.f;
        for (int x = 0; x < 64; ++x) s += partial[t * 64 + x];
        int row = cand[t];
        w[row] = s * INV_SCALE * mask[row];
    }
}

// ---------------------------------------------------------------------------
__global__ __launch_bounds__(1024) void softmax_k(
    const float* __restrict__ w, float* __restrict__ p)
{
    const int b = blockIdx.x;
    const float* wr = w + (long)b * NN;
    float* pr = p + (long)b * NN;
    const int t = threadIdx.x;
    __shared__ float red[16];
    __shared__ float bmax, bsum;

    float m = -3.4e38f;
    for (int i = t; i < NN; i += 1024) m = fmaxf(m, wr[i]);
#pragma unroll
    for (int o = 32; o > 0; o >>= 1) m = fmaxf(m, __shfl_down(m, o));
    if ((t & 63) == 0) red[t >> 6] = m;
    __syncthreads();
    if (t == 0) {
        float mm = red[0];
        for (int i = 1; i < 16; ++i) mm = fmaxf(mm, red[i]);
        bmax = mm;
    }
    __syncthreads();
    const float M = bmax;

    float s = 0.f;
    for (int i = t; i < NN; i += 1024) s += expf(wr[i] - M);
#pragma unroll
    for (int o = 32; o > 0; o >>= 1) s += __shfl_down(s, o);
    __syncthreads();
    if ((t & 63) == 0) red[t >> 6] = s;
    __syncthreads();
    if (t == 0) {
        float ss = 0.f;
        for (int i = 0; i < 16; ++i) ss += red[i];
        bsum = ss;
    }
    __syncthreads();
    const float invS = 1.f / bsum;
    for (int i = t; i < NN; i += 1024) pr[i] = expf(wr[i] - M) * invS;
}

// ---------------------------------------------------------------------------
extern "C" void kernel_launch(void* const* d_in, const int* in_sizes, int n_in,
                              void* d_out, int out_size, void* d_ws, size_t ws_size,
                              hipStream_t stream)
{
    const float* X    = (const float*)d_in[0];
    const float* adj  = (const float*)d_in[1];
    const float* mask = (const float*)d_in[2];
    const float* Wqk  = (const float*)d_in[3];
    const float* Wv   = (const float*)d_in[4];
    float* out = (float*)d_out;

    char* ws = (char*)d_ws;
    const long SZB = 33554432;  // 16384*512*4 bytes
    float* km_buf = (float*)(ws);                    // fp32 km (refine)
    unsigned short* Xhi = (unsigned short*)(ws + SZB);
    unsigned short* Xlo = Xhi + 8388608;
    unsigned short* qh  = (unsigned short*)(ws + 2 * SZB);            // 16.8 MB
    unsigned short* kmh = qh + 8388608;                               // 16.8 MB
    unsigned short* QTh = kmh + 8388608;             // 4 x 0.5 MB
    unsigned short* KTh = QTh + 262144;
    unsigned short* KTl = KTh + 262144;
    unsigned short* VTh = KTl + 262144;
    float* w_buf = (float*)(VTh + 262144);
    float* p_buf = w_buf + 16384;
    float* partial = p_buf + 16384;                  // 128*64
    float* qcand = partial + 8192;                   // 128*512
    int* count = (int*)(qcand + 65536);
    int* cand  = count + 64;

    hipError_t e0 = hipMemsetAsync(count, 0, 4, stream); (void)e0;
    hipError_t e1 = hipMemsetAsync(w_buf, 0, 16384 * 4, stream); (void)e1;

    convx_k<<<8192, 256, 0, stream>>>(X, Xhi, Xlo);
    convw_k<<<3072, 256, 0, stream>>>(Wqk, Wv, QTh, KTh, KTl, VTh);

    // km = (X @ Wk) * mask  (3-term split) -> km fp32 + kmh bf16
    mfma_gemm<1, 3><<<dim3(128, 4, 1), 256, 0, stream>>>(
        Xhi, Xlo, KTh, KTl, nullptr, km_buf, kmh, mask, 512, 512);

    // q = X @ Wq (single-term bf16) -> qh bf16 (fp32 q only needed per-cand)
    mfma_gemm<2, 1><<<dim3(128, 4, 1), 256, 0, stream>>>(
        Xhi, nullptr, QTh, nullptr, nullptr, nullptr, qh, nullptr, 512, 512);

    // w += sum_j adj_ij * (q_i . km_j): S-GEMM tiles + S-through-LDS sweep
    sq_gemm<<<8192, 256, 0, stream>>>(qh, kmh, adj, w_buf);

    fixup_k<<<64, 256, 0, stream>>>(w_buf, mask);

    wmaxsel_k<<<BB, 256, 0, stream>>>(w_buf, count, cand);
    qcand_k<<<128, 256, 0, stream>>>(X, Wqk, cand, count, qcand);
    refine_k<<<dim3(64, 128, 1), 256, 0, stream>>>(qcand, km_buf, adj, cand, count, partial);
    apply_k<<<1, 128, 0, stream>>>(cand, count, partial, mask, w_buf);

    softmax_k<<<BB, 1024, 0, stream>>>(w_buf, p_buf);

    // out = p * (X @ Wv): v-GEMM moved post-softmax, p fused in epilogue
    mfma_gemm<3, 1><<<dim3(128, 4, 1), 256, 0, stream>>>(
        Xhi, nullptr, VTh, nullptr, out, nullptr, nullptr, p_buf, 512, 512);
}